// Round 4
// baseline (497.116 us; speedup 1.0000x reference)
//
#include <hip/hip_runtime.h>

// SpatialPool: fm [B=16, C=512, H=38, W=38] f32, replication pad 1,
// out[b, (h*W+w)*9*C + k*C + c] = fm[b, c, clamp(h+k/3-1), clamp(w+k%3-1)]
//
// R1-R3 (two-phase LDS kernel, chunked writes): ~185us kernel, ~3 TB/s.
// Scalar->float4 stores neutral; XCD swizzle neutral -> structure-bound.
// R4: two kernels. A: NCHW->NHWC transpose into ws (47 MB).
//     B: pure streaming gather — globally-linear writes (same pattern as
//     the 6.3 TB/s fill), coalesced float4 reads from L3-resident NHWC.

#define BB 16
#define CC 512
#define HH 38
#define WW 38
#define HW (HH * WW)          // 1444
#define KK 9
#define CCH 128
#define NCH (CC / CCH)        // 4
#define LC (CCH + 4)          // 132
#define NT 512

// ---------------- Kernel A: NCHW -> NHWC transpose ----------------
__global__ __launch_bounds__(NT) void nchw_to_nhwc(const float* __restrict__ fm,
                                                   float* __restrict__ nhwc)
{
    __shared__ float lds[WW][LC];            // 38*132*4 = 20,064 B
    const int blk   = blockIdx.x;            // 0..2431
    const int chunk = blk & (NCH - 1);
    const int bh    = blk >> 2;
    const int h     = bh % HH;
    const int b     = bh / HH;
    const int c0    = chunk * CCH;

    const float* base = fm + ((size_t)b * CC + c0) * HW + h * WW;
    const int NL2 = CCH * (WW / 2);          // 2432 float2 loads
    for (int idx = threadIdx.x; idx < NL2; idx += NT) {
        int w2 = idx % (WW / 2);
        int c  = idx / (WW / 2);
        const float2 v = *(const float2*)(base + c * HW + 2 * w2);
        lds[2 * w2 + 0][c] = v.x;
        lds[2 * w2 + 1][c] = v.y;
    }
    __syncthreads();
    float4* dst = (float4*)(nhwc + ((size_t)b * HW + (size_t)h * WW) * CC + c0);
    const int NS = WW * (CCH / 4);           // 1216 float4 stores
    for (int i = threadIdx.x; i < NS; i += NT) {
        int c4 = i & 31;
        int w  = i >> 5;
        dst[(size_t)w * (CC / 4) + c4] = *(const float4*)&lds[w][c4 * 4];
    }
}

// ---------------- Kernel B: pure streaming 3x3 gather ----------------
// out float4 index f -> (b, hw, k, c4); writes linear in f across the grid.
__global__ __launch_bounds__(NT) void gather9(const float* __restrict__ nhwc,
                                              float4* __restrict__ out4)
{
    const int NF4 = BB * HW * KK * (CC / 4); // 26,640,384
    const float4* src = (const float4*)nhwc;
    int f = blockIdx.x * NT + threadIdx.x;
    const int c4 = f & 127;                  // stride is multiple of 128 -> const
    int r = f >> 7;                          // (b*HW+hw)*9 + k
    const int stride_f = gridDim.x * NT;     // 2432*512 = 1,245,184 (mult of 128)
    const int stride_r = stride_f >> 7;      // 9728
    for (; f < NF4; f += stride_f, r += stride_r) {
        unsigned ur = (unsigned)r;
        unsigned q  = ur / 9u;               // b*HW + hw
        unsigned k  = ur - q * 9u;
        unsigned b  = q / (unsigned)HW;
        unsigned hw = q - b * (unsigned)HW;
        unsigned h  = hw / (unsigned)WW;
        unsigned w  = hw - h * (unsigned)WW;
        unsigned di = k / 3u;
        unsigned dj = k - 3u * di;
        int hp = (int)h + (int)di - 1; hp = hp < 0 ? 0 : (hp > HH - 1 ? HH - 1 : hp);
        int wp = (int)w + (int)dj - 1; wp = wp < 0 ? 0 : (wp > WW - 1 ? WW - 1 : wp);
        out4[f] = src[((size_t)b * HW + (size_t)hp * WW + wp) * (CC / 4) + c4];
    }
}

// ---------------- Fallback (R2 single-kernel) if ws too small ----------------
__global__ __launch_bounds__(NT) void spatial_pool_fallback(
    const float* __restrict__ fm, float* __restrict__ out)
{
    __shared__ float lds[3][WW][LC];
    const int blk   = blockIdx.x;
    const int chunk = blk & (NCH - 1);
    const int bh    = blk >> 2;
    const int h     = bh % HH;
    const int b     = bh / HH;
    const int c0    = chunk * CCH;
    const int r0 = (h - 1 < 0) ? 0 : h - 1;
    const int r1 = h;
    const int r2 = (h + 1 > HH - 1) ? HH - 1 : h + 1;
    const float* base = fm + ((size_t)b * CC + c0) * HW;
    const int NL2 = 3 * CCH * (WW / 2);
    for (int idx = threadIdx.x; idx < NL2; idx += NT) {
        int w2 = idx % (WW / 2);
        int rc = idx / (WW / 2);
        int c  = rc & (CCH - 1);
        int r  = rc >> 7;
        int hr = (r == 0) ? r0 : ((r == 1) ? r1 : r2);
        const float2 v = *(const float2*)(base + c * HW + hr * WW + 2 * w2);
        lds[r][2 * w2 + 0][c] = v.x;
        lds[r][2 * w2 + 1][c] = v.y;
    }
    __syncthreads();
    float4* outb4 = (float4*)(out + (((size_t)b * HW + (size_t)h * WW) * KK) * CC + c0);
    const int NST4 = WW * KK * (CCH / 4);
    for (int i = threadIdx.x; i < NST4; i += NT) {
        int c4 = i & 31;
        int wk = i >> 5;
        int w  = wk / KK;
        int k  = wk - w * KK;
        int di = k / 3;
        int dj = k - di * 3;
        int wp = w + dj - 1;
        wp = (wp < 0) ? 0 : ((wp > WW - 1) ? WW - 1 : wp);
        outb4[(size_t)wk * (CC / 4) + c4] = *(const float4*)&lds[di][wp][c4 * 4];
    }
}

extern "C" void kernel_launch(void* const* d_in, const int* in_sizes, int n_in,
                              void* d_out, int out_size, void* d_ws, size_t ws_size,
                              hipStream_t stream) {
    const float* fm = (const float*)d_in[0];
    float* out = (float*)d_out;
    const size_t NHWC_BYTES = (size_t)BB * HW * CC * sizeof(float); // 47,316,992
    if (ws_size >= NHWC_BYTES) {
        float* nhwc = (float*)d_ws;
        nchw_to_nhwc<<<BB * HH * NCH, NT, 0, stream>>>(fm, nhwc);
        gather9<<<2432, NT, 0, stream>>>(nhwc, (float4*)out);
    } else {
        spatial_pool_fallback<<<BB * HH * NCH, NT, 0, stream>>>(fm, out);
    }
}

// Round 5
// 462.600 us; speedup vs baseline: 1.0746x; 1.0746x over previous
//
#include <hip/hip_runtime.h>

// SpatialPool: fm [B=16, C=512, H=38, W=38] f32, replication pad 1,
// out[b, (h*W+w)*9*C + k*C + c] = fm[b, c, clamp(h+k/3-1), clamp(w+k%3-1)]
//
// R1-R4: every gather-style structure (LDS fan-out, float4 stores, XCD
// swizzle, linear-write streaming) lands at ~3 TB/s aggregate.
// R5: SCATTER. Read each input element once (47 MB — the only read),
// fan out in registers to its 9 output slots. With edge-clamp, each
// (h) has exactly 3 h'-targets and each (w) exactly 3 w'-targets ->
// uniformly 9 stores/element, no divergence, no LDS, no barrier.
// Nontemporal stores keep the 426-MB one-touch write stream from
// thrashing L2/L3 (protects input-line reuse).

#define BB 16
#define CC 512
#define HH 38
#define WW 38
#define HW (HH * WW)      // 1444
#define KK 9
#define NT 256
#define NW4 10            // w handled in groups of 4 (last group = 2)

__global__ __launch_bounds__(NT) void spatial_pool_scatter(
    const float* __restrict__ fm, float* __restrict__ out)
{
    // blockIdx -> (w4 fastest [read-line sharing], chalf, b*h)
    const int blk   = blockIdx.x;
    const int w4    = blk % NW4;
    const int t     = blk / NW4;
    const int chalf = t & 1;
    const int bh    = t >> 1;
    const int h     = bh % HH;
    const int b     = bh / HH;
    const int c     = chalf * NT + threadIdx.x;   // lane-consecutive c

    const int w0 = w4 * 4;
    const int nw = (w4 == NW4 - 1) ? 2 : 4;

    // ---- read once: 2x float2 (8B-aligned: 1444c+38h+w0 is even) ----
    const float* src = fm + ((size_t)(b * CC + c)) * HW + h * WW + w0;
    float v[4];
    {
        float2 r0 = *(const float2*)src;
        v[0] = r0.x; v[1] = r0.y;
        if (nw == 4) {
            float2 r1 = *(const float2*)(src + 2);
            v[2] = r1.x; v[3] = r1.y;
        }
    }

    // ---- h-target list: always exactly 3 (clamp extras rebalance) ----
    // hrow = (b*HW + h'*WW)*9 + di*3
    int hrow[3];
    {
        int n = 0;
        #pragma unroll
        for (int di = 0; di < 3; ++di) {
            int hm = h + 1 - di;
            if (0 <= hm && hm < HH) { hrow[n] = (b * HW + hm * WW) * KK + di * 3; n++; }
        }
        if (h == 0)      { hrow[n] = (b * HW) * KK; n++; }                         // di=0,h'=0
        if (h == HH - 1) { hrow[n] = (b * HW + (HH - 1) * WW) * KK + 6; n++; }     // di=2,h'=37
    }

    for (int wi = 0; wi < nw; ++wi) {
        const int w = w0 + wi;
        // w-target list: always exactly 3.  woff = w'*9 + dj
        int woff[3];
        {
            int m = 0;
            #pragma unroll
            for (int dj = 0; dj < 3; ++dj) {
                int wm = w + 1 - dj;
                if (0 <= wm && wm < WW) { woff[m] = wm * KK + dj; m++; }
            }
            if (w == 0)      { woff[m] = 0; m++; }                 // dj=0,w'=0
            if (w == WW - 1) { woff[m] = (WW - 1) * KK + 2; m++; } // dj=2,w'=37
        }
        const float val = v[wi];
        #pragma unroll
        for (int i = 0; i < 3; ++i) {
            #pragma unroll
            for (int j = 0; j < 3; ++j) {
                // element index < 107M: fits unsigned
                unsigned idx = (unsigned)(hrow[i] + woff[j]) * (unsigned)CC + (unsigned)c;
                __builtin_nontemporal_store(val, out + (size_t)idx);
            }
        }
    }
}

extern "C" void kernel_launch(void* const* d_in, const int* in_sizes, int n_in,
                              void* d_out, int out_size, void* d_ws, size_t ws_size,
                              hipStream_t stream) {
    const float* fm = (const float*)d_in[0];
    float* out = (float*)d_out;
    dim3 grid(NW4 * 2 * BB * HH);   // 10 * 2 * 608 = 12160 blocks
    dim3 block(NT);
    spatial_pool_scatter<<<grid, block, 0, stream>>>(fm, out);
}